// Round 3
// baseline (88.748 us; speedup 1.0000x reference)
//
#include <hip/hip_runtime.h>
#include <hip/hip_fp16.h>
#include <stdint.h>

// MultiResolutionHashEncoding, R6: cross-iteration software pipeline.
// R5 post-mortem: occupancy 16->32 waves/CU gave only -2.7% => kernel is NOT
// TLP-starved; the limiter is the serial per-iteration chain
// (addr VALU -> 8 ds_read -> lgkmcnt(0) -> FMA). R6 breaks it: addresses and
// weights for iteration k are computed during iteration k-1, so the 8 LDS
// gathers issue at loop top and their latency overlaps the NEXT iteration's
// address math. x prefetched two iterations ahead. Arithmetic unchanged
// (same hash constants, same fma_mix consume) => absmax identical.
// BLOCK=1024, __launch_bounds__(1024,8): 2 blocks/CU (128 KiB LDS), 32
// waves/CU, VGPR cap 64 (pipeline live set ~50, no spill expected;
// unroll 1 pinned to keep it that way).

#define NUM_LEVELS 16
#define TABLE_SZ   16384
#define NCHUNK     32          // grid = 16 levels * 32 chunks = 512 blocks = 2/CU
#define BLOCK      1024

__constant__ float RESV[NUM_LEVELS] = {
    16.f, 22.f, 30.f, 42.f, 58.f, 80.f, 110.f, 152.f,
    210.f, 290.f, 400.f, 553.f, 763.f, 1053.f, 1453.f, 2005.f
};

// 2654435761 mod 16384 = 14769 ; 805459861 mod 16384 = 6037 (verified).
// (H*v) & 16383 == ((H mod 16384)*v) & 16383; coords <= 2005 so products
// < 2^25 -> __umul24 exact.
#define H2_LO 14769u
#define H3_LO 6037u

// addr+weight computation for one point (px,py,pz) -> named outputs.
#define COMPUTE(PX,PY,PZ, OXY0,OXY1,OXY2,OXY3,MZL,MZH, W0,W1,W2,W3,OZ,WZ)      \
    {                                                                          \
        float wx_ = (PX) - floorf(PX);                                         \
        float wy_ = (PY) - floorf(PY);                                         \
        float wz_ = (PZ) - floorf(PZ);                                         \
        float ox_ = 1.f - wx_, oy_ = 1.f - wy_;                                \
        OZ = 1.f - wz_; WZ = wz_;                                              \
        W0 = ox_ * oy_; W1 = wx_ * oy_; W2 = wx_ * wy_; W3 = ox_ * wy_;        \
        float sx_ = r * (PX), sy_ = r * (PY), sz_ = r * (PZ);                  \
        uint32_t mxl_ = ((uint32_t)(int)floorf(sx_) & (TABLE_SZ - 1)) << 2;    \
        uint32_t mxh_ = ((uint32_t)(int)ceilf(sx_)  & (TABLE_SZ - 1)) << 2;    \
        uint32_t myl_ = (__umul24(H2_LO, (uint32_t)(int)floorf(sy_))           \
                         & (TABLE_SZ - 1)) << 2;                               \
        uint32_t myh_ = (__umul24(H2_LO, (uint32_t)(int)ceilf(sy_))            \
                         & (TABLE_SZ - 1)) << 2;                               \
        MZL = (__umul24(H3_LO, (uint32_t)(int)floorf(sz_))                     \
               & (TABLE_SZ - 1)) << 2;                                         \
        MZH = (__umul24(H3_LO, (uint32_t)(int)ceilf(sz_))                      \
               & (TABLE_SZ - 1)) << 2;                                         \
        OXY0 = mxl_ ^ myl_; OXY1 = mxh_ ^ myl_;                                \
        OXY2 = mxh_ ^ myh_; OXY3 = mxl_ ^ myh_;                                \
    }

__global__ __launch_bounds__(BLOCK, 8)   // 8 waves/EU -> VGPR cap 64
void hashenc_lds_kernel(const float* __restrict__ x,
                        const float* __restrict__ tables,
                        float* __restrict__ out,
                        int B, int pts_per_block)
{
    __shared__ __half2 tab[TABLE_SZ];            // 64 KiB; 2 blocks/CU

    const int level = blockIdx.x >> 5;           // blockIdx = level*NCHUNK + chunk
    const int chunk = blockIdx.x & (NCHUNK - 1);

    // ---- stage: global f32 table -> LDS f16 ----
    {
        const float4* __restrict__ gt4 =
            (const float4*)(tables + (size_t)level * (TABLE_SZ * 2));
        #pragma unroll
        for (int i = threadIdx.x; i < TABLE_SZ / 2; i += BLOCK) {
            float4 v = gt4[i];
            tab[2 * i]     = __floats2half2_rn(v.x, v.y);
            tab[2 * i + 1] = __floats2half2_rn(v.z, v.w);
        }
    }
    __syncthreads();

    const float r = RESV[level];
    const int b0 = chunk * pts_per_block + threadIdx.x;
    const int iters = pts_per_block / BLOCK;     // 8192/1024 = 8

    const float* __restrict__ xp = x + 3 * (size_t)b0;      // this thread's x
    const float* __restrict__ xf = xp + 3 * 2 * BLOCK;      // prefetch k+2 ptr
    float2* __restrict__ op = (float2*)out + (size_t)b0 * NUM_LEVELS + level;
    const char* tb = (const char*)tab;

    // ---- prologue: compute iter-0 state, prefetch x for iter 1 ----
    float px = xp[0], py = xp[1], pz = xp[2];
    uint32_t c_oxy0, c_oxy1, c_oxy2, c_oxy3, c_mzl, c_mzh;
    float    c_w0, c_w1, c_w2, c_w3, c_oz, c_wz;
    COMPUTE(px, py, pz, c_oxy0, c_oxy1, c_oxy2, c_oxy3, c_mzl, c_mzh,
            c_w0, c_w1, c_w2, c_w3, c_oz, c_wz);

    float nx = px, ny = py, nz = pz;
    if (iters > 1) {
        nx = xp[3 * BLOCK + 0];
        ny = xp[3 * BLOCK + 1];
        nz = xp[3 * BLOCK + 2];
    }

    #pragma unroll 1
    for (int k = 0; k < iters; ++k) {
        // -- 1. issue the 8 gathers for iteration k (addresses ready) --
        __half2 h0 = *(const __half2*)(tb + (c_oxy0 ^ c_mzl));
        __half2 h1 = *(const __half2*)(tb + (c_oxy1 ^ c_mzl));
        __half2 h2 = *(const __half2*)(tb + (c_oxy2 ^ c_mzl));
        __half2 h3 = *(const __half2*)(tb + (c_oxy3 ^ c_mzl));
        __half2 h4 = *(const __half2*)(tb + (c_oxy0 ^ c_mzh));
        __half2 h5 = *(const __half2*)(tb + (c_oxy1 ^ c_mzh));
        __half2 h6 = *(const __half2*)(tb + (c_oxy2 ^ c_mzh));
        __half2 h7 = *(const __half2*)(tb + (c_oxy3 ^ c_mzh));

        // -- 2. prefetch x for iteration k+2 --
        float fx = nx, fy = ny, fz = nz;
        if (k + 2 < iters) {
            nx = xf[0]; ny = xf[1]; nz = xf[2];
        }
        xf += 3 * BLOCK;

        // -- 3. compute iter k+1 addresses/weights (overlaps DS latency) --
        uint32_t n_oxy0, n_oxy1, n_oxy2, n_oxy3, n_mzl, n_mzh;
        float    n_w0, n_w1, n_w2, n_w3, n_oz, n_wz;
        COMPUTE(fx, fy, fz, n_oxy0, n_oxy1, n_oxy2, n_oxy3, n_mzl, n_mzh,
                n_w0, n_w1, n_w2, n_w3, n_oz, n_wz);

        // -- 4. consume gathers with iter-k weights --
        float a0 = 0.f, a1 = 0.f;
        {
            float w0 = c_w0 * c_oz, w1 = c_w1 * c_oz,
                  w2 = c_w2 * c_oz, w3 = c_w3 * c_oz;
            a0 = fmaf(__low2float(h0),  w0, a0);
            a1 = fmaf(__high2float(h0), w0, a1);
            a0 = fmaf(__low2float(h1),  w1, a0);
            a1 = fmaf(__high2float(h1), w1, a1);
            a0 = fmaf(__low2float(h2),  w2, a0);
            a1 = fmaf(__high2float(h2), w2, a1);
            a0 = fmaf(__low2float(h3),  w3, a0);
            a1 = fmaf(__high2float(h3), w3, a1);
        }
        {
            float w0 = c_w0 * c_wz, w1 = c_w1 * c_wz,
                  w2 = c_w2 * c_wz, w3 = c_w3 * c_wz;
            a0 = fmaf(__low2float(h4),  w0, a0);
            a1 = fmaf(__high2float(h4), w0, a1);
            a0 = fmaf(__low2float(h5),  w1, a0);
            a1 = fmaf(__high2float(h5), w1, a1);
            a0 = fmaf(__low2float(h6),  w2, a0);
            a1 = fmaf(__high2float(h6), w2, a1);
            a0 = fmaf(__low2float(h7),  w3, a0);
            a1 = fmaf(__high2float(h7), w3, a1);
        }

        // out[b][level]; stride per iter = BLOCK rows (L2 merges the 8B
        // scatters; verified R2: WRITE_SIZE == ideal 32768 KB)
        *op = make_float2(a0, a1);
        op += (size_t)BLOCK * NUM_LEVELS;

        // -- rotate pipeline state --
        c_oxy0 = n_oxy0; c_oxy1 = n_oxy1; c_oxy2 = n_oxy2; c_oxy3 = n_oxy3;
        c_mzl = n_mzl; c_mzh = n_mzh;
        c_w0 = n_w0; c_w1 = n_w1; c_w2 = n_w2; c_w3 = n_w3;
        c_oz = n_oz; c_wz = n_wz;
    }
}

extern "C" void kernel_launch(void* const* d_in, const int* in_sizes, int n_in,
                              void* d_out, int out_size, void* d_ws, size_t ws_size,
                              hipStream_t stream) {
    const float* x      = (const float*)d_in[0];
    const float* tables = (const float*)d_in[1];
    float* out          = (float*)d_out;
    int B = in_sizes[0] / 3;
    int pts_per_block = (B + NCHUNK - 1) / NCHUNK;   // 8192 for B=262144
    dim3 grid(NUM_LEVELS * NCHUNK);
    hashenc_lds_kernel<<<grid, BLOCK, 0, stream>>>(x, tables, out, B, pts_per_block);
}

// Round 4
// 88.305 us; speedup vs baseline: 1.0050x; 1.0050x over previous
//
#include <hip/hip_runtime.h>
#include <hip/hip_fp16.h>
#include <stdint.h>

// MultiResolutionHashEncoding, R7: pipeline the DS READS, not just addresses.
// R6 post-mortem: addr-pipelining neutral (88.7 vs 87.8) — the per-iter
// blocking wait is the ds_read round-trip itself: 32 lockstep waves burst
// 256 reads/CU into the DS queue and each wave stalls ~1000+ cyc on its
// lgkmcnt. R7 double-buffers the 8 gather registers: issue iter-k reads,
// compute iter-(k+1) addresses, consume iter-(k-1) data (issued ~1600 cyc
// ago -> lgkmcnt(8) never blocks). Bit-identical arithmetic to R5/R6.
// __launch_bounds__(1024,4): VGPR cap 128 (pipeline live set ~70; R5 showed
// occupancy 32->16 waves/CU costs only ~3%, spills would cost far more).

#define NUM_LEVELS 16
#define TABLE_SZ   16384
#define NCHUNK     32          // grid = 16 levels * 32 chunks = 512 blocks
#define BLOCK      1024

__constant__ float RESV[NUM_LEVELS] = {
    16.f, 22.f, 30.f, 42.f, 58.f, 80.f, 110.f, 152.f,
    210.f, 290.f, 400.f, 553.f, 763.f, 1053.f, 1453.f, 2005.f
};

// 2654435761 mod 16384 = 14769 ; 805459861 mod 16384 = 6037 (verified).
// (H*v) & 16383 == ((H mod 16384)*v) & 16383; coords <= 2005 so products
// < 2^25 -> __umul24 exact.
#define H2_LO 14769u
#define H3_LO 6037u

// addr+weight computation for one point (px,py,pz) -> named outputs.
#define COMPUTE(PX,PY,PZ, OXY0,OXY1,OXY2,OXY3,MZL,MZH, W0,W1,W2,W3,OZ,WZ)      \
    {                                                                          \
        float wx_ = (PX) - floorf(PX);                                         \
        float wy_ = (PY) - floorf(PY);                                         \
        float wz_ = (PZ) - floorf(PZ);                                         \
        float ox_ = 1.f - wx_, oy_ = 1.f - wy_;                                \
        OZ = 1.f - wz_; WZ = wz_;                                              \
        W0 = ox_ * oy_; W1 = wx_ * oy_; W2 = wx_ * wy_; W3 = ox_ * wy_;        \
        float sx_ = r * (PX), sy_ = r * (PY), sz_ = r * (PZ);                  \
        uint32_t mxl_ = ((uint32_t)(int)floorf(sx_) & (TABLE_SZ - 1)) << 2;    \
        uint32_t mxh_ = ((uint32_t)(int)ceilf(sx_)  & (TABLE_SZ - 1)) << 2;    \
        uint32_t myl_ = (__umul24(H2_LO, (uint32_t)(int)floorf(sy_))           \
                         & (TABLE_SZ - 1)) << 2;                               \
        uint32_t myh_ = (__umul24(H2_LO, (uint32_t)(int)ceilf(sy_))            \
                         & (TABLE_SZ - 1)) << 2;                               \
        MZL = (__umul24(H3_LO, (uint32_t)(int)floorf(sz_))                     \
               & (TABLE_SZ - 1)) << 2;                                         \
        MZH = (__umul24(H3_LO, (uint32_t)(int)ceilf(sz_))                      \
               & (TABLE_SZ - 1)) << 2;                                         \
        OXY0 = mxl_ ^ myl_; OXY1 = mxh_ ^ myl_;                                \
        OXY2 = mxh_ ^ myh_; OXY3 = mxl_ ^ myh_;                                \
    }

// issue the 8 gathers for a state into named __half2 regs
#define ISSUE(H0,H1,H2,H3,H4,H5,H6,H7, OXY0,OXY1,OXY2,OXY3,MZL,MZH)            \
    {                                                                          \
        H0 = *(const __half2*)(tb + ((OXY0) ^ (MZL)));                         \
        H1 = *(const __half2*)(tb + ((OXY1) ^ (MZL)));                         \
        H2 = *(const __half2*)(tb + ((OXY2) ^ (MZL)));                         \
        H3 = *(const __half2*)(tb + ((OXY3) ^ (MZL)));                         \
        H4 = *(const __half2*)(tb + ((OXY0) ^ (MZH)));                         \
        H5 = *(const __half2*)(tb + ((OXY1) ^ (MZH)));                         \
        H6 = *(const __half2*)(tb + ((OXY2) ^ (MZH)));                         \
        H7 = *(const __half2*)(tb + ((OXY3) ^ (MZH)));                         \
    }

// trilinear consume (identical expression order to R5/R6 -> same absmax)
#define CONSUME(H0,H1,H2,H3,H4,H5,H6,H7, W0,W1,W2,W3,OZ,WZ, A0,A1)             \
    {                                                                          \
        float q0 = (W0) * (OZ), q1 = (W1) * (OZ),                              \
              q2 = (W2) * (OZ), q3 = (W3) * (OZ);                              \
        A0 = fmaf(__low2float(H0),  q0, A0);                                   \
        A1 = fmaf(__high2float(H0), q0, A1);                                   \
        A0 = fmaf(__low2float(H1),  q1, A0);                                   \
        A1 = fmaf(__high2float(H1), q1, A1);                                   \
        A0 = fmaf(__low2float(H2),  q2, A0);                                   \
        A1 = fmaf(__high2float(H2), q2, A1);                                   \
        A0 = fmaf(__low2float(H3),  q3, A0);                                   \
        A1 = fmaf(__high2float(H3), q3, A1);                                   \
        float p0 = (W0) * (WZ), p1 = (W1) * (WZ),                              \
              p2 = (W2) * (WZ), p3 = (W3) * (WZ);                              \
        A0 = fmaf(__low2float(H4),  p0, A0);                                   \
        A1 = fmaf(__high2float(H4), p0, A1);                                   \
        A0 = fmaf(__low2float(H5),  p1, A0);                                   \
        A1 = fmaf(__high2float(H5), p1, A1);                                   \
        A0 = fmaf(__low2float(H6),  p2, A0);                                   \
        A1 = fmaf(__high2float(H6), p2, A1);                                   \
        A0 = fmaf(__low2float(H7),  p3, A0);                                   \
        A1 = fmaf(__high2float(H7), p3, A1);                                   \
    }

__global__ __launch_bounds__(BLOCK, 4)   // VGPR cap 128; no-spill priority
void hashenc_lds_kernel(const float* __restrict__ x,
                        const float* __restrict__ tables,
                        float* __restrict__ out,
                        int B, int pts_per_block)
{
    __shared__ __half2 tab[TABLE_SZ];            // 64 KiB

    const int level = blockIdx.x >> 5;           // blockIdx = level*NCHUNK + chunk
    const int chunk = blockIdx.x & (NCHUNK - 1);

    // ---- stage: global f32 table -> LDS f16 ----
    {
        const float4* __restrict__ gt4 =
            (const float4*)(tables + (size_t)level * (TABLE_SZ * 2));
        #pragma unroll
        for (int i = threadIdx.x; i < TABLE_SZ / 2; i += BLOCK) {
            float4 v = gt4[i];
            tab[2 * i]     = __floats2half2_rn(v.x, v.y);
            tab[2 * i + 1] = __floats2half2_rn(v.z, v.w);
        }
    }
    __syncthreads();

    const float r = RESV[level];
    const int b0 = chunk * pts_per_block + threadIdx.x;
    const int iters = pts_per_block / BLOCK;     // 8192/1024 = 8

    const float* __restrict__ xp = x + 3 * (size_t)b0;
    const float* __restrict__ xf = xp + 3 * (size_t)(3 * BLOCK);  // x for k+2, k>=1
    float2* __restrict__ op = (float2*)out + (size_t)b0 * NUM_LEVELS + level;
    const size_t opstride = (size_t)BLOCK * NUM_LEVELS;
    const char* tb = (const char*)tab;

    // ---- prologue ----
    // iter 0: compute state, issue its reads (in-flight set hp*, weights aw*)
    float px = xp[0], py = xp[1], pz = xp[2];
    uint32_t t0, t1, t2, t3, t4, t5;             // iter-0 addrs (transient)
    float aw0, aw1, aw2, aw3, aoz, awz;          // in-flight weights
    COMPUTE(px, py, pz, t0, t1, t2, t3, t4, t5, aw0, aw1, aw2, aw3, aoz, awz);
    __half2 hp0, hp1, hp2, hp3, hp4, hp5, hp6, hp7;   // in-flight data
    ISSUE(hp0, hp1, hp2, hp3, hp4, hp5, hp6, hp7, t0, t1, t2, t3, t4, t5);

    // iter 1: state ready-to-issue (c_*)
    float x1x = px, x1y = py, x1z = pz;
    if (iters > 1) {
        x1x = xp[3 * BLOCK + 0];
        x1y = xp[3 * BLOCK + 1];
        x1z = xp[3 * BLOCK + 2];
    }
    uint32_t c0, c1, c2, c3, c4, c5;
    float cw0, cw1, cw2, cw3, coz, cwz;
    COMPUTE(x1x, x1y, x1z, c0, c1, c2, c3, c4, c5, cw0, cw1, cw2, cw3, coz, cwz);

    // x for iter 2
    float fx = px, fy = py, fz = pz;
    if (iters > 2) {
        fx = xp[6 * BLOCK + 0];
        fy = xp[6 * BLOCK + 1];
        fz = xp[6 * BLOCK + 2];
    }

    #pragma unroll 2
    for (int k = 1; k < iters; ++k) {
        // 1. issue iter-k reads (addresses in c_*) into hc*
        __half2 hc0, hc1, hc2, hc3, hc4, hc5, hc6, hc7;
        ISSUE(hc0, hc1, hc2, hc3, hc4, hc5, hc6, hc7, c0, c1, c2, c3, c4, c5);

        // 2. x bookkeeping: gx = x_{k+1}; refill fx = x_{k+2}
        float gx = fx, gy = fy, gz = fz;
        if (k + 2 < iters) {
            fx = xf[0]; fy = xf[1]; fz = xf[2];
        }
        xf += 3 * BLOCK;

        // 3. compute iter-(k+1) state (overlaps DS latency of hc*)
        uint32_t n0, n1, n2, n3, n4, n5;
        float nw0, nw1, nw2, nw3, noz, nwz;
        COMPUTE(gx, gy, gz, n0, n1, n2, n3, n4, n5, nw0, nw1, nw2, nw3, noz, nwz);

        // 4. consume iter-(k-1) data (issued a full iteration ago ->
        //    s_waitcnt lgkmcnt(8), non-blocking in steady state)
        float a0 = 0.f, a1 = 0.f;
        CONSUME(hp0, hp1, hp2, hp3, hp4, hp5, hp6, hp7,
                aw0, aw1, aw2, aw3, aoz, awz, a0, a1);
        *op = make_float2(a0, a1);
        op += opstride;

        // 5. rotate pipeline registers (compiler renames under unroll 2)
        hp0 = hc0; hp1 = hc1; hp2 = hc2; hp3 = hc3;
        hp4 = hc4; hp5 = hc5; hp6 = hc6; hp7 = hc7;
        aw0 = cw0; aw1 = cw1; aw2 = cw2; aw3 = cw3; aoz = coz; awz = cwz;
        c0 = n0; c1 = n1; c2 = n2; c3 = n3; c4 = n4; c5 = n5;
        cw0 = nw0; cw1 = nw1; cw2 = nw2; cw3 = nw3; coz = noz; cwz = nwz;
    }

    // ---- epilogue: consume final in-flight iteration ----
    {
        float a0 = 0.f, a1 = 0.f;
        CONSUME(hp0, hp1, hp2, hp3, hp4, hp5, hp6, hp7,
                aw0, aw1, aw2, aw3, aoz, awz, a0, a1);
        *op = make_float2(a0, a1);
    }
}

extern "C" void kernel_launch(void* const* d_in, const int* in_sizes, int n_in,
                              void* d_out, int out_size, void* d_ws, size_t ws_size,
                              hipStream_t stream) {
    const float* x      = (const float*)d_in[0];
    const float* tables = (const float*)d_in[1];
    float* out          = (float*)d_out;
    int B = in_sizes[0] / 3;
    int pts_per_block = (B + NCHUNK - 1) / NCHUNK;   // 8192 for B=262144
    dim3 grid(NUM_LEVELS * NCHUNK);
    hashenc_lds_kernel<<<grid, BLOCK, 0, stream>>>(x, tables, out, B, pts_per_block);
}